// Round 1
// baseline (1415.915 us; speedup 1.0000x reference)
//
#include <hip/hip_runtime.h>
#include <cmath>

#define CC 21
#define HH 512
#define WW 512
#define HWSZ (HH*WW)
#define CHW (CC*HWSZ)
#define NITERS 5

struct K9 { float k[9]; };

// q[c,h,w] = unaries[0,h,w,c]
__global__ void init_q_kernel(const float* __restrict__ unaries, float* __restrict__ q) {
    int p = blockIdx.x * 256 + threadIdx.x;
    if (p >= HWSZ) return;
    #pragma unroll
    for (int c = 0; c < CC; ++c) q[c*HWSZ + p] = unaries[p*CC + c];
}

// M = CM @ (SKW + BKW)   (both blurs are identical since theta_gamma==theta_beta)
__global__ void precomp_M_kernel(const float* __restrict__ skw, const float* __restrict__ bkw,
                                 const float* __restrict__ cm, float* __restrict__ M) {
    int i = blockIdx.x * blockDim.x + threadIdx.x;
    if (i >= CC*CC) return;
    int r = i / CC, k = i - r*CC;
    float a = 0.f;
    for (int j = 0; j < CC; ++j) a += cm[r*CC + j] * (skw[j*CC + k] + bkw[j*CC + k]);
    M[i] = a;
}

__global__ void softmax_kernel(const float* __restrict__ q, float* __restrict__ sm) {
    int p = blockIdx.x * 256 + threadIdx.x;
    if (p >= HWSZ) return;
    float v[CC];
    float m = -1e30f;
    #pragma unroll
    for (int c = 0; c < CC; ++c) { v[c] = q[c*HWSZ + p]; m = fmaxf(m, v[c]); }
    float s = 0.f;
    #pragma unroll
    for (int c = 0; c < CC; ++c) { v[c] = expf(v[c] - m); s += v[c]; }
    float inv = 1.f / s;
    #pragma unroll
    for (int c = 0; c < CC; ++c) sm[c*HWSZ + p] = v[c] * inv;
}

// red layout: [0..20] sum1, [21..41] sum2, [42] n1, [43] n2
// mask at sm-pixel (h,w) is (sp_map[0][w][h] == idx); iterate sp_map linearly:
// p = y*W + x  ->  sm pixel (h=x, w=y)
__global__ void reduce_kernel(const float* __restrict__ sm, const int* __restrict__ sp_map,
                              const int* __restrict__ sp_indices, int iter,
                              float* __restrict__ red) {
    int p = blockIdx.x * 256 + threadIdx.x;
    if (p >= HWSZ) return;
    int idx = sp_indices[iter];
    int lab = sp_map[p];
    if (lab != idx && lab != idx + 1) return;
    int y = p >> 9, x = p & (WW - 1);
    int sp = x * WW + y;
    int off = (lab == idx) ? 0 : 21;
    atomicAdd(&red[42 + ((lab == idx) ? 0 : 1)], 1.f);
    for (int c = 0; c < CC; ++c) atomicAdd(&red[off + c], expf(sm[c*HWSZ + sp]));
}

// B[c] = log((HW - n1) + sum1[c]);  B[C+c] likewise for mask2
__global__ void finalize_kernel(const float* __restrict__ red, float* __restrict__ B) {
    int c = threadIdx.x;
    if (c >= CC) return;
    float n1 = red[42], n2 = red[43];
    B[c]      = logf((float)HWSZ - n1 + red[c]);
    B[CC + c] = logf((float)HWSZ - n2 + red[21 + c]);
}

// vertical 9-tap blur, zero pad: tmp[c,h,w] = sum_t k[t]*sm[c,h+t-4,w]
__global__ void vblur_kernel(const float* __restrict__ sm, float* __restrict__ tmp, K9 kk) {
    int i = blockIdx.x * 256 + threadIdx.x;
    if (i >= CHW) return;
    int c = i >> 18;              // / HWSZ
    int p = i & (HWSZ - 1);
    int h = p >> 9;
    int w = p & (WW - 1);
    float acc = 0.f;
    #pragma unroll
    for (int t = 0; t < 9; ++t) {
        int hh = h + t - 4;
        if (hh >= 0 && hh < HH) acc += kk.k[t] * sm[c*HWSZ + hh*WW + w];
    }
    tmp[i] = acc;
}

// Fused: horizontal blur (from LDS row tile) -> /norm -> M@ -> attachment -> q = u - pw - att
// sm and qout alias (same buffer, same-pixel read-then-write only) -> NOT __restrict__.
__launch_bounds__(256)
__global__ void final_kernel(const float* __restrict__ tmp, const float* sm,
                             float* qout, float* __restrict__ outHWC,
                             const float* __restrict__ unaries, const int* __restrict__ sp_map,
                             const int* __restrict__ sp_indices, int iter,
                             const float* __restrict__ Mg, const float* __restrict__ Bg,
                             const float* __restrict__ lwg, const float* __restrict__ hwg,
                             K9 kk, int last) {
    __shared__ float tile[CC][264];
    __shared__ float Ms[CC*CC];
    __shared__ float Bs[2*CC];
    __shared__ float lws[2*CC];
    __shared__ float hws[2];

    int bid = blockIdx.x;
    int h  = bid >> 1;
    int w0 = (bid & 1) * 256;
    int tx = threadIdx.x;

    for (int i = tx; i < CC*CC; i += 256) Ms[i] = Mg[i];
    if (tx < 2*CC) { Bs[tx] = Bg[tx]; lws[tx] = lwg[tx]; }
    if (tx < 2) hws[tx] = hwg[tx];
    for (int c = 0; c < CC; ++c) {
        for (int j = tx; j < 264; j += 256) {
            int gw = w0 - 4 + j;
            tile[c][j] = (gw >= 0 && gw < WW) ? tmp[c*HWSZ + h*WW + gw] : 0.f;
        }
    }
    __syncthreads();

    int w = w0 + tx;
    int p = h*WW + w;

    // horizontal blur per channel (registers)
    float b[CC];
    #pragma unroll
    for (int c = 0; c < CC; ++c) {
        float a = 0.f;
        #pragma unroll
        for (int t = 0; t < 9; ++t) a += kk.k[t] * tile[c][tx + t];
        b[c] = a;
    }

    // separable norm = s(h)*s(w), s(i) = sum of in-range taps
    float sv = 0.f, sw = 0.f;
    #pragma unroll
    for (int t = 0; t < 9; ++t) {
        int hh = h + t - 4; if (hh >= 0 && hh < HH) sv += kk.k[t];
        int wi = w + t - 4; if (wi >= 0 && wi < WW) sw += kk.k[t];
    }
    float invnorm = 1.f / (sv * sw);

    int idxv = sp_indices[iter];
    int lab  = sp_map[w*WW + h];      // transposed sp_map
    float hw0 = hws[0], hw1 = hws[1];

    for (int c = 0; c < CC; ++c) {
        float pw = 0.f;
        #pragma unroll
        for (int k = 0; k < CC; ++k) pw += Ms[c*CC + k] * b[k];
        pw *= invnorm;

        float smv = sm[c*HWSZ + p];
        float qm  = (smv == 0.f) ? 1.f : smv;
        float ft1 = (lab == idxv)     ? Bs[c]      / qm : 0.f;
        float ft2 = (lab == idxv + 1) ? Bs[CC + c] / qm : 0.f;
        float fta = ft1 + ft2;                    // masks disjoint
        float att = lws[c]*ft1 + hw0*(1.f - ft1) + lws[CC + c]*fta + hw1*(1.f - fta);

        float u  = unaries[p*CC + c];
        float qn = u - pw - att;
        if (last) outHWC[p*CC + c] = qn;
        else      qout[c*HWSZ + p] = qn;
    }
}

extern "C" void kernel_launch(void* const* d_in, const int* in_sizes, int n_in,
                              void* d_out, int out_size, void* d_ws, size_t ws_size,
                              hipStream_t stream) {
    const float* unaries    = (const float*)d_in[0];
    // d_in[1] = rgb (unused by the reference)
    const int*   sp_map     = (const int*)d_in[2];
    const int*   sp_indices = (const int*)d_in[3];
    const float* skw        = (const float*)d_in[4];
    const float* bkw        = (const float*)d_in[5];
    const float* cm         = (const float*)d_in[6];
    const float* lw         = (const float*)d_in[7];
    const float* hwt        = (const float*)d_in[8];
    float* out = (float*)d_out;

    float* ws   = (float*)d_ws;
    float* buf0 = ws;                  // q / tmp
    float* buf1 = ws + CHW;            // sm / q_new
    float* M    = ws + 2*(size_t)CHW;  // 441
    float* red  = M + CC*CC;           // 44
    float* B    = red + 44;            // 42

    // 9-tap normalized Gaussian, sigma=3 (fp32, matches reference)
    K9 kk;
    {
        float s = 0.f;
        for (int t = 0; t < 9; ++t) {
            float x = (float)(t - 4) / 3.0f;
            kk.k[t] = expf(-0.5f * x * x);
            s += kk.k[t];
        }
        for (int t = 0; t < 9; ++t) kk.k[t] /= s;
    }

    init_q_kernel<<<HWSZ/256, 256, 0, stream>>>(unaries, buf0);
    precomp_M_kernel<<<2, 256, 0, stream>>>(skw, bkw, cm, M);

    float* qb = buf0;
    float* ob = buf1;
    for (int it = 0; it < NITERS; ++it) {
        hipMemsetAsync(red, 0, 44*sizeof(float), stream);
        softmax_kernel<<<HWSZ/256, 256, 0, stream>>>(qb, ob);          // sm -> ob
        reduce_kernel<<<HWSZ/256, 256, 0, stream>>>(ob, sp_map, sp_indices, it, red);
        finalize_kernel<<<1, 32, 0, stream>>>(red, B);
        vblur_kernel<<<CHW/256, 256, 0, stream>>>(ob, qb, kk);          // tmp -> qb (old q dead)
        int last = (it == NITERS - 1);
        final_kernel<<<HWSZ/256, 256, 0, stream>>>(qb, ob, ob, out, unaries, sp_map,
                                                   sp_indices, it, M, B, lw, hwt, kk, last);
        float* t_ = qb; qb = ob; ob = t_;                               // q now in ob
    }
}

// Round 2
// 586.362 us; speedup vs baseline: 2.4147x; 2.4147x over previous
//
#include <hip/hip_runtime.h>
#include <cmath>

#define CC 21
#define HH 512
#define WW 512
#define HWSZ (HH*WW)
#define CHW (CC*HWSZ)
#define NITERS 5
#define RBLOCKS 256   // reduce blocks (1024 threads each covers HWSZ exactly)

struct K9 { float k[9]; };

// q[c,h,w] = unaries[0,h,w,c]
__global__ void init_q_kernel(const float* __restrict__ unaries, float* __restrict__ q) {
    int p = blockIdx.x * 256 + threadIdx.x;
    if (p >= HWSZ) return;
    #pragma unroll
    for (int c = 0; c < CC; ++c) q[c*HWSZ + p] = unaries[p*CC + c];
}

// M = CM @ (SKW + BKW)   (both blurs identical since theta_gamma==theta_beta)
__global__ void precomp_M_kernel(const float* __restrict__ skw, const float* __restrict__ bkw,
                                 const float* __restrict__ cm, float* __restrict__ M) {
    int i = blockIdx.x * blockDim.x + threadIdx.x;
    if (i >= CC*CC) return;
    int r = i / CC, k = i - r*CC;
    float a = 0.f;
    for (int j = 0; j < CC; ++j) a += cm[r*CC + j] * (skw[j*CC + k] + bkw[j*CC + k]);
    M[i] = a;
}

__global__ void softmax_kernel(const float* __restrict__ q, float* __restrict__ sm) {
    int p = blockIdx.x * 256 + threadIdx.x;
    if (p >= HWSZ) return;
    float v[CC];
    float m = -1e30f;
    #pragma unroll
    for (int c = 0; c < CC; ++c) { v[c] = q[c*HWSZ + p]; m = fmaxf(m, v[c]); }
    float s = 0.f;
    #pragma unroll
    for (int c = 0; c < CC; ++c) { v[c] = expf(v[c] - m); s += v[c]; }
    float inv = 1.f / s;
    #pragma unroll
    for (int c = 0; c < CC; ++c) sm[c*HWSZ + p] = v[c] * inv;
}

// Per-block LDS accumulation -> non-atomic partials. part layout: [RBLOCKS][44]
// slot 0..20 = sum1[c], 21..41 = sum2[c], 42 = n1, 43 = n2
// mask at sm-pixel (h,w) is (sp_map[0][w][h] == idx): iterate sp_map linearly,
// p = y*W + x  ->  sm pixel (h=x, w=y) -> sp = x*W + y
__launch_bounds__(1024)
__global__ void reduce_kernel(const float* __restrict__ sm, const int* __restrict__ sp_map,
                              const int* __restrict__ sp_indices, int iter,
                              float* __restrict__ part) {
    __shared__ float acc[44];
    int tx = threadIdx.x;
    if (tx < 44) acc[tx] = 0.f;
    __syncthreads();
    int p = blockIdx.x * 1024 + tx;
    int idx = sp_indices[iter];
    int lab = sp_map[p];
    if (lab == idx || lab == idx + 1) {
        int y = p >> 9, x = p & (WW - 1);
        int sp = x * WW + y;
        int m = (lab == idx) ? 0 : 1;
        atomicAdd(&acc[42 + m], 1.f);
        for (int c = 0; c < CC; ++c) atomicAdd(&acc[m*21 + c], expf(sm[c*HWSZ + sp]));
    }
    __syncthreads();
    if (tx < 44) part[blockIdx.x*44 + tx] = acc[tx];
}

// B[t<21] = log(HW - n1 + sum1[c]);  B[21+c] likewise for mask2
__global__ void finalize_kernel(const float* __restrict__ part, float* __restrict__ B) {
    __shared__ float sums[44];
    int t = threadIdx.x;   // 64 threads
    if (t < 44) {
        float s = 0.f;
        for (int b = 0; b < RBLOCKS; ++b) s += part[b*44 + t];
        sums[t] = s;
    }
    __syncthreads();
    if (t < 42) {
        int m = t / 21;
        float n = sums[42 + m];
        B[t] = logf((float)HWSZ - n + sums[t]);
    }
}

// vertical 9-tap blur, zero pad: tmp[c,h,w] = sum_t k[t]*sm[c,h+t-4,w]
__global__ void vblur_kernel(const float* __restrict__ sm, float* __restrict__ tmp, K9 kk) {
    int i = blockIdx.x * 256 + threadIdx.x;
    if (i >= CHW) return;
    int c = i >> 18;              // / HWSZ
    int p = i & (HWSZ - 1);
    int h = p >> 9;
    float acc = 0.f;
    #pragma unroll
    for (int t = 0; t < 9; ++t) {
        int hh = h + t - 4;
        if (hh >= 0 && hh < HH) acc += kk.k[t] * sm[i + (t - 4)*WW];
    }
    tmp[i] = acc;
}

// Fused: horizontal blur (from LDS row tile) -> /norm -> M@ -> attachment -> q = u - pw - att
// sm and qout alias (same buffer, same-pixel read-then-write only) -> NOT __restrict__.
__launch_bounds__(256)
__global__ void final_kernel(const float* __restrict__ tmp, const float* sm,
                             float* qout, float* __restrict__ outHWC,
                             const float* __restrict__ unaries, const int* __restrict__ sp_map,
                             const int* __restrict__ sp_indices, int iter,
                             const float* __restrict__ Mg, const float* __restrict__ Bg,
                             const float* __restrict__ lwg, const float* __restrict__ hwg,
                             K9 kk, int last) {
    __shared__ float tile[CC][264];
    __shared__ float Ms[CC*CC];
    __shared__ float Bs[2*CC];
    __shared__ float lws[2*CC];
    __shared__ float hws[2];

    int bid = blockIdx.x;
    int h  = bid >> 1;
    int w0 = (bid & 1) * 256;
    int tx = threadIdx.x;

    for (int i = tx; i < CC*CC; i += 256) Ms[i] = Mg[i];
    if (tx < 2*CC) { Bs[tx] = Bg[tx]; lws[tx] = lwg[tx]; }
    if (tx < 2) hws[tx] = hwg[tx];
    for (int c = 0; c < CC; ++c) {
        for (int j = tx; j < 264; j += 256) {
            int gw = w0 - 4 + j;
            tile[c][j] = (gw >= 0 && gw < WW) ? tmp[c*HWSZ + h*WW + gw] : 0.f;
        }
    }
    __syncthreads();

    int w = w0 + tx;
    int p = h*WW + w;

    // horizontal blur per channel (registers)
    float b[CC];
    #pragma unroll
    for (int c = 0; c < CC; ++c) {
        float a = 0.f;
        #pragma unroll
        for (int t = 0; t < 9; ++t) a += kk.k[t] * tile[c][tx + t];
        b[c] = a;
    }

    // separable norm = s(h)*s(w), s(i) = sum of in-range taps
    float sv = 0.f, sw = 0.f;
    #pragma unroll
    for (int t = 0; t < 9; ++t) {
        int hh = h + t - 4; if (hh >= 0 && hh < HH) sv += kk.k[t];
        int wi = w + t - 4; if (wi >= 0 && wi < WW) sw += kk.k[t];
    }
    float invnorm = 1.f / (sv * sw);

    int idxv = sp_indices[iter];
    int lab  = sp_map[w*WW + h];      // transposed sp_map
    float hw0 = hws[0], hw1 = hws[1];

    for (int c = 0; c < CC; ++c) {
        float pw = 0.f;
        #pragma unroll
        for (int k = 0; k < CC; ++k) pw += Ms[c*CC + k] * b[k];
        pw *= invnorm;

        float smv = sm[c*HWSZ + p];
        float qm  = (smv == 0.f) ? 1.f : smv;
        float ft1 = (lab == idxv)     ? Bs[c]      / qm : 0.f;
        float ft2 = (lab == idxv + 1) ? Bs[CC + c] / qm : 0.f;
        float fta = ft1 + ft2;                    // masks disjoint
        float att = lws[c]*ft1 + hw0*(1.f - ft1) + lws[CC + c]*fta + hw1*(1.f - fta);

        float u  = unaries[p*CC + c];
        float qn = u - pw - att;
        if (last) outHWC[p*CC + c] = qn;
        else      qout[c*HWSZ + p] = qn;
    }
}

extern "C" void kernel_launch(void* const* d_in, const int* in_sizes, int n_in,
                              void* d_out, int out_size, void* d_ws, size_t ws_size,
                              hipStream_t stream) {
    const float* unaries    = (const float*)d_in[0];
    // d_in[1] = rgb (unused by the reference)
    const int*   sp_map     = (const int*)d_in[2];
    const int*   sp_indices = (const int*)d_in[3];
    const float* skw        = (const float*)d_in[4];
    const float* bkw        = (const float*)d_in[5];
    const float* cm         = (const float*)d_in[6];
    const float* lw         = (const float*)d_in[7];
    const float* hwt        = (const float*)d_in[8];
    float* out = (float*)d_out;

    float* ws   = (float*)d_ws;
    float* buf0 = ws;                  // q / tmp
    float* buf1 = ws + CHW;            // sm / q_new
    float* M    = ws + 2*(size_t)CHW;  // 441
    float* part = M + CC*CC;           // RBLOCKS*44
    float* B    = part + RBLOCKS*44;   // 42

    // 9-tap normalized Gaussian, sigma=3 (fp32, matches reference)
    K9 kk;
    {
        float s = 0.f;
        for (int t = 0; t < 9; ++t) {
            float x = (float)(t - 4) / 3.0f;
            kk.k[t] = expf(-0.5f * x * x);
            s += kk.k[t];
        }
        for (int t = 0; t < 9; ++t) kk.k[t] /= s;
    }

    init_q_kernel<<<HWSZ/256, 256, 0, stream>>>(unaries, buf0);
    precomp_M_kernel<<<2, 256, 0, stream>>>(skw, bkw, cm, M);

    float* qb = buf0;
    float* ob = buf1;
    for (int it = 0; it < NITERS; ++it) {
        softmax_kernel<<<HWSZ/256, 256, 0, stream>>>(qb, ob);          // sm -> ob
        reduce_kernel<<<RBLOCKS, 1024, 0, stream>>>(ob, sp_map, sp_indices, it, part);
        finalize_kernel<<<1, 64, 0, stream>>>(part, B);
        vblur_kernel<<<CHW/256, 256, 0, stream>>>(ob, qb, kk);          // tmp -> qb (old q dead)
        int last = (it == NITERS - 1);
        final_kernel<<<HWSZ/256, 256, 0, stream>>>(qb, ob, ob, out, unaries, sp_map,
                                                   sp_indices, it, M, B, lw, hwt, kk, last);
        float* t_ = qb; qb = ob; ob = t_;                               // q now in ob
    }
}